// Round 8
// baseline (140.550 us; speedup 1.0000x reference)
//
#include <hip/hip_runtime.h>
#include <hip/hip_bf16.h>

// BatchedNLM: per-neuron 2-layer GLU MLP.
//   state_trace (128,2048,32) f32, fc1_w (2048,32,256), fc1_b (2048,256),
//   fc2_w (2048,128,2), fc2_b (2048,2), T (1)  ->  out (128,2048) f32
//
// R14: nlm's w1 staging switched from global_load_lds DMA to tight-liveness
// REGISTER staging: thread (h=t&255, kh=t>>8) issues 16 independent dword
// loads (256B/instr wave-coalesced, 16 outstanding per thread = 8x the MLP
// of the 4-DMA/wave path), cvt_pk -> 8 u32, two ds_write_b128 into the
// fragment-major bf16 buffer. Deletes ldsW (LDS 34.8->18.9 KB) and 2 of 3
// barriers. Theory H: the LDS-DMA path (4 instrs/wave + vmcnt(0) drain)
// was the ~40us invariant's cause — too little memory parallelism per wave,
// and the drain convoys all 8 waves. The fast kernels this session (fills
// 6.6 TB/s, R7's spill storm 2.6 TB/s) all use many independent per-thread
// loads; every ~40us variant used the DMA.
//
// History:
// R4/R7/R9/R11 FAILED: register-staging w1 with LONG cross-phase liveness
//     under a tight VGPR cap spills. Toolchain quirk: __launch_bounds__(X,4)
//     caps VGPR at 64 (3x confirmed); (X,2) -> cap 128. R14's staging has
//     ~24 regs transient liveness under the 128 cap — not the same animal.
// R5: DMA introduced (94->46us, but vs a spilling baseline). R6 ~40us.
// R8/R10 NEUTRAL (41-45us): occupancy x2 / cross-neuron pipelining -> no
//     change; all pipes idle. R12/R13: st gather split out as streaming
//     bf16 transpose (k1) -> nlm ~35-39us. Scatter theory mostly dead.
//     Remaining suspect: the DMA staging path itself. R14 tests it.

#define NN 2048

typedef __attribute__((ext_vector_type(8))) short short8;
typedef __attribute__((ext_vector_type(4))) float floatx4;
typedef __attribute__((ext_vector_type(4))) int int4v;

static __device__ __forceinline__ unsigned int pkbf(float a, float b) {
    __hip_bfloat162 h = __float22bfloat162_rn(make_float2(a, b));  // v_cvt_pk_bf16_f32
    return *(unsigned int*)&h;
}

static __device__ __forceinline__ float sigmoidf_(float x) {
    return __builtin_amdgcn_rcpf(1.0f + __expf(-x));  // mul+exp+add+rcp
}

// ---------------------------------------------------------------------------
// k1: st (128,2048,32) f32  ->  st_t bf16, fragment-major per neuron.
// st_t short index: n*4096 + mt*512 + quad*128 + m*8 + e
//   holds st[b = mt*16 + m][n][k = quad*8 + e] as bf16.
// Wave <-> (n, mt); lane: m = lane&15, quad = lane>>4.
//   read : 32B/lane contig (16 x 128B segments per wave instr, L2-friendly)
//   write: 16B/lane -> 1KB fully contiguous per wave instr.
// No LDS, no barriers, 8 independent iters/wave -> latency-immune.
// (unchanged from R13)
// ---------------------------------------------------------------------------
__global__ __launch_bounds__(256)
void st_transpose_kernel(const float* __restrict__ st, short* __restrict__ st_t)
{
    const int t    = threadIdx.x;       // 0..255
    const int lane = t & 63;
    const int wv   = t >> 6;            // 0..3
    const int mt   = blockIdx.x & 7;    // batch tile
    const int g    = blockIdx.x >> 3;   // 0..63 n-group
    const int m    = lane & 15;
    const int quad = lane >> 4;

    const int b = mt * 16 + m;
    const float* src = st + (size_t)b * (NN * 32) + (size_t)quad * 8;
    short* dstbase = st_t + (size_t)mt * 512 + (size_t)lane * 8;

    const int n0 = g * 32 + wv;         // wave handles n = n0 + 4*i, i<8
    #pragma unroll
    for (int i = 0; i < 8; ++i) {
        const int n = n0 + i * 4;
        floatx4 a0 = *(const floatx4*)(src + (size_t)n * 32);
        floatx4 a1 = *(const floatx4*)(src + (size_t)n * 32 + 4);
        union { int4v iv; short8 s; } u;
        u.iv[0] = pkbf(a0[0], a0[1]);
        u.iv[1] = pkbf(a0[2], a0[3]);
        u.iv[2] = pkbf(a1[0], a1[1]);
        u.iv[3] = pkbf(a1[2], a1[3]);
        *(short8*)(dstbase + (size_t)n * 4096) = u.s;
    }
}

// ---------------------------------------------------------------------------
// nlm: one block per neuron, 512 thr = 8 waves, wave wv owns batch tile mt=wv.
// ---------------------------------------------------------------------------
__global__ __launch_bounds__(512, 2)
void nlm_kernel(const short* __restrict__ st_t,
                const float* __restrict__ w1,
                const float* __restrict__ b1,
                const float* __restrict__ w2,
                const float* __restrict__ b2,
                const float* __restrict__ Tp,
                float* __restrict__ out_t)
{
    const int n = blockIdx.x;
    const int t = threadIdx.x;     // 0..511

    __shared__ __align__(16) short ldsB[8192];   // 16 KB bf16 W1, frag-major
    __shared__ float4 ldsP[128];   // {b1[h], b1[128+h], w2[2h], w2[2h+1]}
    __shared__ float  ldsO[128];
    // 18944 B total

    const int lane = t & 63;
    const int wv   = t >> 6;      // wave 0..7 = batch tile mt
    const int m    = lane & 15;   // A row / C col
    const int quad = lane >> 4;   // k-quad / C row group

    // ---- 1) afrag: ONE dense coalesced 16B load, layout-ready bf16 ----
    short8 afrag = *(const short8*)(st_t + (size_t)n * 4096 + wv * 512 + lane * 8);

    // ---- 2) params ----
    if (t < 128) {
        const float* b1p = b1 + (size_t)n * 256;
        const float* w2p = w2 + (size_t)n * 256;
        float  pba = b1p[t];
        float  pbb = b1p[128 + t];
        float2 pw2 = *(const float2*)(w2p + 2 * t);
        ldsP[t] = make_float4(pba, pbb, pw2.x, pw2.y);
    }
    const float bb0  = b2[n * 2 + 0];
    const float bb1  = b2[n * 2 + 1];
    const float invT = 1.0f / Tp[0];

    // ---- 3) W1 reg-staging: thread (h = t&255, kh = t>>8) owns column h,
    //         k-rows [16kh, 16kh+16). 16 independent dword loads (wave:
    //         256B/instr coalesced, 16 in flight), cvt_pk pairs along k,
    //         two ds_write_b128 into fragment-major layout:
    //         short idx = (h>>4)*512 + (k>>3)*128 + (h&15)*8 + (k&7). ----
    {
        const int h  = t & 255;
        const int kh = t >> 8;
        const float* gW = w1 + (size_t)n * 8192 + (size_t)kh * 16 * 256 + h;
        float wr[16];
        #pragma unroll
        for (int j = 0; j < 16; ++j)
            wr[j] = gW[(size_t)j * 256];

        const int base = ((h >> 4) * 512) + ((h & 15) * 8) + kh * 256;
        #pragma unroll
        for (int q = 0; q < 2; ++q) {
            union { int4v iv; short8 s; } u;
            #pragma unroll
            for (int e = 0; e < 4; ++e)
                u.iv[e] = pkbf(wr[q * 8 + 2 * e], wr[q * 8 + 2 * e + 1]);
            *(short8*)&ldsB[base + q * 128] = u.s;
        }
    }

    __syncthreads();   // the ONLY staging barrier (ldsB + ldsP visible)

    // ---- 4) Compute: 8 tile-pairs, fc1 bias as MFMA C-init, fc2 folded ----
    float pacc[4][2];
    #pragma unroll
    for (int r = 0; r < 4; ++r)
        pacc[r][0] = pacc[r][1] = 0.0f;

    #pragma unroll
    for (int p = 0; p < 8; ++p) {
        short8 bfA = *(short8*)&ldsB[(p * 64 + lane) * 8];
        short8 bfB = *(short8*)&ldsB[((p + 8) * 64 + lane) * 8];
        float4 prm = ldsP[p * 16 + m];   // {bias_a, bias_b, w2a, w2b}, h=16p+m
        floatx4 ca = {prm.x, prm.x, prm.x, prm.x};
        floatx4 cb = {prm.y, prm.y, prm.y, prm.y};
        floatx4 xa = __builtin_amdgcn_mfma_f32_16x16x32_bf16(afrag, bfA, ca, 0, 0, 0);
        floatx4 xb = __builtin_amdgcn_mfma_f32_16x16x32_bf16(afrag, bfB, cb, 0, 0, 0);
        #pragma unroll
        for (int r = 0; r < 4; ++r) {
            float glu = xa[r] * sigmoidf_(xb[r]);
            pacc[r][0] += glu * prm.z;
            pacc[r][1] += glu * prm.w;
        }
    }

    // ---- 5) Reduce fc2 partials across the 16 lanes of each quad ----
    #pragma unroll
    for (int r = 0; r < 4; ++r) {
        float s0 = pacc[r][0];
        float s1 = pacc[r][1];
        s0 += __shfl_xor(s0, 1);  s1 += __shfl_xor(s1, 1);
        s0 += __shfl_xor(s0, 2);  s1 += __shfl_xor(s1, 2);
        s0 += __shfl_xor(s0, 4);  s1 += __shfl_xor(s1, 4);
        s0 += __shfl_xor(s0, 8);  s1 += __shfl_xor(s1, 8);
        if (m == 0) {
            const int b = wv * 16 + quad * 4 + r;
            float x0 = s0 + bb0;
            float x1 = s1 + bb1;
            ldsO[b] = x0 * sigmoidf_(x1) * invT;
        }
    }

    __syncthreads();

    // One coalesced 512B row per block into out_t (2048,128).
    if (t < 128)
        out_t[(size_t)n * 128 + t] = ldsO[t];
}

// Transpose out_t (2048,128) -> out (128,2048). 32x32 tiles, 256 blocks.
__global__ __launch_bounds__(256)
void transpose_kernel(const float* __restrict__ out_t, float* __restrict__ out)
{
    __shared__ float tile[32][33];
    const int t    = threadIdx.x;
    const int bidx = blockIdx.x;           // 0..255
    const int n0   = (bidx & 63) * 32;     // 64 n-tiles
    const int b0   = (bidx >> 6) * 32;     // 4 b-tiles

    const int tx = t & 31;
    const int ty = t >> 5;                 // 0..7

    #pragma unroll
    for (int i = 0; i < 4; ++i) {
        const int nl = ty + i * 8;
        tile[nl][tx] = out_t[(size_t)(n0 + nl) * 128 + b0 + tx];
    }

    __syncthreads();

    #pragma unroll
    for (int i = 0; i < 4; ++i) {
        const int bl = ty + i * 8;
        out[(size_t)(b0 + bl) * NN + n0 + tx] = tile[tx][bl];
    }
}

extern "C" void kernel_launch(void* const* d_in, const int* in_sizes, int n_in,
                              void* d_out, int out_size, void* d_ws, size_t ws_size,
                              hipStream_t stream) {
    const float* st = (const float*)d_in[0];
    const float* w1 = (const float*)d_in[1];
    const float* b1 = (const float*)d_in[2];
    const float* w2 = (const float*)d_in[3];
    const float* b2 = (const float*)d_in[4];
    const float* T  = (const float*)d_in[5];
    float* out   = (float*)d_out;
    float* out_t = (float*)d_ws;                         // [0, 1 MB)
    short* st_t  = (short*)((char*)d_ws + (2u << 20));   // [2 MB, 2+16.8 MB)

    st_transpose_kernel<<<dim3(512), dim3(256), 0, stream>>>(st, st_t);
    nlm_kernel<<<dim3(NN), dim3(512), 0, stream>>>(st_t, w1, b1, w2, b2, T, out_t);
    transpose_kernel<<<dim3(256), dim3(256), 0, stream>>>(out_t, out);
}